// Round 15
// baseline (95.008 us; speedup 1.0000x reference)
//
#include <hip/hip_runtime.h>

#define BATCHES 4
#define NPTS    8192
#define INF32   3.0e38f
#define REPEAT  4   // DIAGNOSTIC: x4 inner work (idempotent min) to lift
                    // chamfer_mfma above the ~40us fill dispatches in rocprof.
                    // Single-pass time = (total - ~11us overhead) / 4.

typedef _Float16 f16x8  __attribute__((ext_vector_type(8)));
typedef float    f32x16 __attribute__((ext_vector_type(16)));

// ---------------- prep: pack A-format and B-format 16-slot f16 vectors ----
// A-vec (pt p):  [ph0..2, pl0..2, ph0..2, qh, ql, 1, 1, 0,0,0]
// B-vec (pt p):  [-2ph0..2, -2ph0..2, -2pl0..2, 1, 1, qh, ql, 0,0,0]
// dot(Avec(u), Bvec(v)) = |u|^2 + |v|^2 - 2*(uh.vh + ul.vh + uh.vl)  (err ~1e-5)
__device__ inline void fsplit(float v, _Float16& h, _Float16& l) {
    h = (_Float16)v;
    l = (_Float16)(v - (float)h);
}

__device__ inline void pack_point(float p0, float p1, float p2,
                                  _Float16* __restrict__ avec,
                                  _Float16* __restrict__ bvec)
{
    _Float16 h[3], l[3];
    fsplit(p0, h[0], l[0]); fsplit(p1, h[1], l[1]); fsplit(p2, h[2], l[2]);
    float q = fmaf(p2, p2, fmaf(p1, p1, p0 * p0));
    _Float16 qh, ql;
    fsplit(q, qh, ql);

    __align__(16) _Float16 av[16];
    __align__(16) _Float16 bv[16];
    #pragma unroll
    for (int k = 0; k < 3; ++k) {
        av[k]     = h[k];
        av[3 + k] = l[k];
        av[6 + k] = h[k];
        bv[k]     = (_Float16)(-2.0f * (float)h[k]);
        bv[3 + k] = bv[k];
        bv[6 + k] = (_Float16)(-2.0f * (float)l[k]);
    }
    av[9] = qh; av[10] = ql; av[11] = (_Float16)1.0f; av[12] = (_Float16)1.0f;
    bv[9] = (_Float16)1.0f; bv[10] = (_Float16)1.0f; bv[11] = qh; bv[12] = ql;
    av[13] = av[14] = av[15] = (_Float16)0.0f;
    bv[13] = bv[14] = bv[15] = (_Float16)0.0f;

    ((int4*)avec)[0] = ((int4*)av)[0]; ((int4*)avec)[1] = ((int4*)av)[1];
    ((int4*)bvec)[0] = ((int4*)bv)[0]; ((int4*)bvec)[1] = ((int4*)bv)[1];
}

__global__ __launch_bounds__(256) void chamfer_prep(
    const float* __restrict__ x, const float* __restrict__ y,
    _Float16* __restrict__ pAx, _Float16* __restrict__ pBx,
    _Float16* __restrict__ pAy, _Float16* __restrict__ pBy,
    int* __restrict__ mininit /* 65536 ints */)
{
    int i = blockIdx.x * 256 + threadIdx.x;     // point id 0..32767
    mininit[i]         = 0x7F7F7F7F;
    mininit[i + 32768] = 0x7F7F7F7F;

    const float* xp = x + (size_t)i * 3;
    const float* yp = y + (size_t)i * 3;
    pack_point(xp[0], xp[1], xp[2], pAx + (size_t)i * 16, pBx + (size_t)i * 16);
    pack_point(yp[0], yp[1], yp[2], pAy + (size_t)i * 16, pBy + (size_t)i * 16);
}

// ---------------- main: dual GEMM, E/O acc double-buffer -------------------
// grid 2048 = dir(2) x batch(4) x rowstrip(64: 128 rows) x colchunk(4: 2048)
// 256 thr = 4 waves; wave owns ONE 32-row A-tile, loops 64 col-tiles as 32
// pairs with TWO explicit acc buffers (accA*, accB*): while pair B's MFMAs
// execute, pair A's results are consumed by 16 v_min3 -- breaks the WAR
// hazard chain (suspected R5-R14 stall: same-reg acc reuse serializes
// MFMA -> min -> MFMA). Live ~112 regs < 128 cap at (256,4). unroll 1.
// A-frag: lane(row=l&31, k=(l>>5)*8+i); B-frag: lane(col=l&31, same k).
// D: col=l&31, row=(reg&3)+8*(reg>>2)+4*(l>>5)  [m74/m101].
__global__ __launch_bounds__(256, 4) void chamfer_mfma(
    const _Float16* __restrict__ pAx, const _Float16* __restrict__ pBx,
    const _Float16* __restrict__ pAy, const _Float16* __restrict__ pBy,
    float* __restrict__ minall /* [2][4][8192] */)
{
    int bid      = blockIdx.x;
    int dir      = bid >> 10;
    int b        = (bid >> 8) & 3;
    int rowstrip = (bid >> 2) & 63;    // 128 rows per block
    int colchunk = bid & 3;            // 2048 cols per block (64 tiles)
    int tid      = threadIdx.x;
    int wv       = tid >> 6, lane = tid & 63;
    int lo       = lane & 31, hi = lane >> 5;

    const _Float16* Adata = ((dir == 0) ? pAx : pAy) + (size_t)b * NPTS * 16;
    const _Float16* Bdata = ((dir == 0) ? pBy : pBx) + (size_t)b * NPTS * 16;
    float* outMin = minall + ((size_t)dir << 15) + (size_t)b * NPTS;

    int rw = rowstrip * 128 + wv * 32;   // wave's 32-row A-tile
    int c0 = colchunk * 2048;            // block's col base (64 tiles of 32)

    f16x8 af = *(const f16x8*)(Adata + ((size_t)(rw + lo) << 4) + (hi << 3));

    float rmin[16];
    #pragma unroll
    for (int r = 0; r < 16; ++r) rmin[r] = INF32;

    const f32x16 zero = {0.f,0.f,0.f,0.f,0.f,0.f,0.f,0.f,
                         0.f,0.f,0.f,0.f,0.f,0.f,0.f,0.f};

    auto loadB = [&](int t) -> f16x8 {   // t = col-tile 0..63
        return *(const f16x8*)(Bdata + ((size_t)(c0 + (t << 5) + lo) << 4) + (hi << 3));
    };

#define MIN3X16(P0, P1)                                                \
    _Pragma("unroll")                                                  \
    for (int r = 0; r < 16; ++r)                                       \
        rmin[r] = fminf(fminf(P0[r], P1[r]), rmin[r]);   /* v_min3 */

    #pragma unroll 1
    for (int rep = 0; rep < REPEAT; ++rep) {
        // prologue: pair P0 in flight, P1 frags loaded
        f16x8 bcA0 = loadB(0), bcA1 = loadB(1);
        f32x16 accA0 = __builtin_amdgcn_mfma_f32_32x32x16_f16(af, bcA0, zero, 0, 0, 0);
        f32x16 accA1 = __builtin_amdgcn_mfma_f32_32x32x16_f16(af, bcA1, zero, 0, 0, 0);
        f16x8 bcB0 = loadB(2), bcB1 = loadB(3);
        f32x16 accB0, accB1;

        // iter q: consume P(2q),P(2q+1); issue P(2q+1),P(2q+2); load P(2q+2),P(2q+3)
        #pragma unroll 1
        for (int q = 0; q < 15; ++q) {
            accB0 = __builtin_amdgcn_mfma_f32_32x32x16_f16(af, bcB0, zero, 0, 0, 0);
            accB1 = __builtin_amdgcn_mfma_f32_32x32x16_f16(af, bcB1, zero, 0, 0, 0);
            bcA0 = loadB(4 * q + 4); bcA1 = loadB(4 * q + 5);
            MIN3X16(accA0, accA1)                    // pair 2q
            accA0 = __builtin_amdgcn_mfma_f32_32x32x16_f16(af, bcA0, zero, 0, 0, 0);
            accA1 = __builtin_amdgcn_mfma_f32_32x32x16_f16(af, bcA1, zero, 0, 0, 0);
            bcB0 = loadB(4 * q + 6); bcB1 = loadB(4 * q + 7);
            MIN3X16(accB0, accB1)                    // pair 2q+1
        }
        // epilogue: P31 issue, consume P30, P31
        accB0 = __builtin_amdgcn_mfma_f32_32x32x16_f16(af, bcB0, zero, 0, 0, 0);
        accB1 = __builtin_amdgcn_mfma_f32_32x32x16_f16(af, bcB1, zero, 0, 0, 0);
        MIN3X16(accA0, accA1)
        MIN3X16(accB0, accB1)
    }
#undef MIN3X16

    // fold row-mins across the 32 col positions (lane bits 0-4), atomicMin
    #pragma unroll
    for (int r = 0; r < 16; ++r) {
        float v = rmin[r];
        v = fminf(v, __shfl_xor(v, 1, 64));
        v = fminf(v, __shfl_xor(v, 2, 64));
        v = fminf(v, __shfl_xor(v, 4, 64));
        v = fminf(v, __shfl_xor(v, 8, 64));
        v = fminf(v, __shfl_xor(v, 16, 64));
        if (lo == 0) {
            int rr = (r & 3) + ((r >> 2) << 3) + (hi << 2);
            atomicMin((int*)&outMin[rw + rr], __float_as_int(fmaxf(v, 0.f)));
        }
    }
}

// ---------------- fused final reduction (one kernel, fixed tree) -----------
__global__ __launch_bounds__(1024) void chamfer_reduce(
    const float* __restrict__ minbuf, float* __restrict__ out)
{
    int tid = threadIdx.x;
    double s = 0.0;
    #pragma unroll
    for (int q = 0; q < 16; ++q) {      // 16 float4 per thread, fixed order
        float4 v = *reinterpret_cast<const float4*>(minbuf + (q * 1024 + tid) * 4);
        s += ((double)v.x + (double)v.y) + ((double)v.z + (double)v.w);
    }
    #pragma unroll
    for (int off = 32; off > 0; off >>= 1) s += __shfl_down(s, off, 64);
    __shared__ double sd[16];
    if ((tid & 63) == 0) sd[tid >> 6] = s;
    __syncthreads();
    if (tid == 0) {
        double t = 0.0;
        #pragma unroll
        for (int w = 0; w < 16; ++w) t += sd[w];
        out[0] = (float)(t / (double)(BATCHES * NPTS));
    }
}

extern "C" void kernel_launch(void* const* d_in, const int* in_sizes, int n_in,
                              void* d_out, int out_size, void* d_ws, size_t ws_size,
                              hipStream_t stream)
{
    const float* x = (const float*)d_in[0];
    const float* y = (const float*)d_in[1];
    float* out = (float*)d_out;

    // ws layout (~4.3 MB):
    float*    minall = (float*)d_ws;                       // 65536 f = 256 KB
    _Float16* pAx = (_Float16*)(minall + 65536);           // 1 MB each
    _Float16* pBx = pAx + (size_t)BATCHES * NPTS * 16;
    _Float16* pAy = pBx + (size_t)BATCHES * NPTS * 16;
    _Float16* pBy = pAy + (size_t)BATCHES * NPTS * 16;

    chamfer_prep<<<BATCHES * NPTS / 256, 256, 0, stream>>>(
        x, y, pAx, pBx, pAy, pBy, (int*)minall);
    chamfer_mfma<<<2048, 256, 0, stream>>>(pAx, pBx, pAy, pBy, minall);
    chamfer_reduce<<<1, 1024, 0, stream>>>(minall, out);
}

// Round 17
// 44.603 us; speedup vs baseline: 2.1301x; 2.1301x over previous
//
#include <hip/hip_runtime.h>

#define BATCHES 4
#define NPTS    8192
#define INF32   3.0e38f

typedef _Float16 f16x8  __attribute__((ext_vector_type(8)));
typedef float    f32x16 __attribute__((ext_vector_type(16)));

// ---------------- prep: pack A-format and B-format 16-slot f16 vectors ----
// A-vec (pt p):  [ph0..2, pl0..2, ph0..2, qh, ql, 1, 1, 0,0,0]
// B-vec (pt p):  [-2ph0..2, -2ph0..2, -2pl0..2, 1, 1, qh, ql, 0,0,0]
// dot(Avec(u), Bvec(v)) = |u|^2 + |v|^2 - 2*(uh.vh + ul.vh + uh.vl)  (err ~1e-5)
__device__ inline void fsplit(float v, _Float16& h, _Float16& l) {
    h = (_Float16)v;
    l = (_Float16)(v - (float)h);
}

__device__ inline void pack_point(float p0, float p1, float p2,
                                  _Float16* __restrict__ avec,
                                  _Float16* __restrict__ bvec)
{
    _Float16 h[3], l[3];
    fsplit(p0, h[0], l[0]); fsplit(p1, h[1], l[1]); fsplit(p2, h[2], l[2]);
    float q = fmaf(p2, p2, fmaf(p1, p1, p0 * p0));
    _Float16 qh, ql;
    fsplit(q, qh, ql);

    __align__(16) _Float16 av[16];
    __align__(16) _Float16 bv[16];
    #pragma unroll
    for (int k = 0; k < 3; ++k) {
        av[k]     = h[k];
        av[3 + k] = l[k];
        av[6 + k] = h[k];
        bv[k]     = (_Float16)(-2.0f * (float)h[k]);
        bv[3 + k] = bv[k];
        bv[6 + k] = (_Float16)(-2.0f * (float)l[k]);
    }
    av[9] = qh; av[10] = ql; av[11] = (_Float16)1.0f; av[12] = (_Float16)1.0f;
    bv[9] = (_Float16)1.0f; bv[10] = (_Float16)1.0f; bv[11] = qh; bv[12] = ql;
    av[13] = av[14] = av[15] = (_Float16)0.0f;
    bv[13] = bv[14] = bv[15] = (_Float16)0.0f;

    ((int4*)avec)[0] = ((int4*)av)[0]; ((int4*)avec)[1] = ((int4*)av)[1];
    ((int4*)bvec)[0] = ((int4*)bv)[0]; ((int4*)bvec)[1] = ((int4*)bv)[1];
}

__global__ __launch_bounds__(256) void chamfer_prep(
    const float* __restrict__ x, const float* __restrict__ y,
    _Float16* __restrict__ pAx, _Float16* __restrict__ pBx,
    _Float16* __restrict__ pAy, _Float16* __restrict__ pBy,
    int* __restrict__ mininit /* 65536 ints */)
{
    int i = blockIdx.x * 256 + threadIdx.x;     // point id 0..32767
    mininit[i]         = 0x7F7F7F7F;
    mininit[i + 32768] = 0x7F7F7F7F;

    const float* xp = x + (size_t)i * 3;
    const float* yp = y + (size_t)i * 3;
    pack_point(xp[0], xp[1], xp[2], pAx + (size_t)i * 16, pBx + (size_t)i * 16);
    pack_point(yp[0], yp[1], yp[2], pAy + (size_t)i * 16, pBy + (size_t)i * 16);
}

// ---------------- main: dual GEMM, 2-pair-deep B prefetch pipeline ---------
// grid 4096 = dir(2) x batch(4) x rowstrip(64: 128 rows) x colchunk(8: 1024)
// 256 thr = 4 waves; wave owns ONE 32-row A-tile, loops 32 col-tiles as 16
// pairs. Pipeline invariant at iter i: accP = results(pair 2i),
// bc0 = frags(pair 2i+1), bc1 = frags(pair 2i+2). Loads run 2 pairs ahead
// of the consuming MFMA (R15's stall: load->use distance was only ~40
// issue-cyc -> vmcnt stall ~250cyc x2/iter; now ~1 full iter x 4 waves).
// Tail loads wrap (&31) -- valid memory, values unused.
// fminf chains only (R16 lesson: inline-asm min3 on MFMA results corrupts).
// Live ~112 regs -> (256,4), R15-proven no-spill. Static names (rule #20).
// A-frag: lane(row=l&31, k=(l>>5)*8+i); B-frag: lane(col=l&31, same k).
// D: col=l&31, row=(reg&3)+8*(reg>>2)+4*(l>>5)  [m74/m101].
__global__ __launch_bounds__(256, 4) void chamfer_mfma(
    const _Float16* __restrict__ pAx, const _Float16* __restrict__ pBx,
    const _Float16* __restrict__ pAy, const _Float16* __restrict__ pBy,
    float* __restrict__ minall /* [2][4][8192] */)
{
    int bid      = blockIdx.x;
    int dir      = bid >> 11;
    int b        = (bid >> 9) & 3;
    int rowstrip = (bid >> 3) & 63;    // 128 rows per block
    int colchunk = bid & 7;            // 1024 cols per block (32 tiles)
    int tid      = threadIdx.x;
    int wv       = tid >> 6, lane = tid & 63;
    int lo       = lane & 31, hi = lane >> 5;

    const _Float16* Adata = ((dir == 0) ? pAx : pAy) + (size_t)b * NPTS * 16;
    const _Float16* Bdata = ((dir == 0) ? pBy : pBx) + (size_t)b * NPTS * 16;
    float* outMin = minall + ((size_t)dir << 15) + (size_t)b * NPTS;

    int rw = rowstrip * 128 + wv * 32;   // wave's 32-row A-tile
    int c0 = colchunk * 1024;            // block's col base (32 tiles of 32)

    f16x8 af = *(const f16x8*)(Adata + ((size_t)(rw + lo) << 4) + (hi << 3));

    float rmin[16];
    #pragma unroll
    for (int r = 0; r < 16; ++r) rmin[r] = INF32;

    const f32x16 zero = {0.f,0.f,0.f,0.f,0.f,0.f,0.f,0.f,
                         0.f,0.f,0.f,0.f,0.f,0.f,0.f,0.f};

    auto loadB = [&](int t) -> f16x8 {   // t = col-tile 0..31 (wrapped)
        return *(const f16x8*)(Bdata + ((size_t)(c0 + ((t & 31) << 5) + lo) << 4)
                               + (hi << 3));
    };

#define MIN16(P0, P1)                                                  \
    _Pragma("unroll")                                                  \
    for (int r = 0; r < 16; ++r)                                       \
        rmin[r] = fminf(fminf(P0[r], P1[r]), rmin[r]);

    // prologue: accP = pair0 in flight; bc0 = pair1 frags; bc1 = pair2 frags
    f16x8 p00 = loadB(0), p01 = loadB(1);
    f16x8 bc0_0 = loadB(2), bc0_1 = loadB(3);
    f16x8 bc1_0 = loadB(4), bc1_1 = loadB(5);
    f32x16 accP0 = __builtin_amdgcn_mfma_f32_32x32x16_f16(af, p00, zero, 0, 0, 0);
    f32x16 accP1 = __builtin_amdgcn_mfma_f32_32x32x16_f16(af, p01, zero, 0, 0, 0);
    f32x16 accQ0, accQ1;

    // iter i: consume pairs 2i, 2i+1; issue 2i+1, 2i+2; load 2i+3, 2i+4
    #pragma unroll 1
    for (int i = 0; i < 7; ++i) {
        accQ0 = __builtin_amdgcn_mfma_f32_32x32x16_f16(af, bc0_0, zero, 0, 0, 0);
        accQ1 = __builtin_amdgcn_mfma_f32_32x32x16_f16(af, bc0_1, zero, 0, 0, 0);
        bc0_0 = loadB(4 * i + 6); bc0_1 = loadB(4 * i + 7);   // pair 2i+3
        MIN16(accP0, accP1)                                   // pair 2i
        accP0 = __builtin_amdgcn_mfma_f32_32x32x16_f16(af, bc1_0, zero, 0, 0, 0);
        accP1 = __builtin_amdgcn_mfma_f32_32x32x16_f16(af, bc1_1, zero, 0, 0, 0);
        bc1_0 = loadB(4 * i + 8); bc1_1 = loadB(4 * i + 9);   // pair 2i+4
        MIN16(accQ0, accQ1)                                   // pair 2i+1
    }
    // after loop: accP = pair14 results; bc0 = pair15 frags (bc1 = wrapped, unused)
    accQ0 = __builtin_amdgcn_mfma_f32_32x32x16_f16(af, bc0_0, zero, 0, 0, 0);
    accQ1 = __builtin_amdgcn_mfma_f32_32x32x16_f16(af, bc0_1, zero, 0, 0, 0);
    MIN16(accP0, accP1)                                       // pair 14
    MIN16(accQ0, accQ1)                                       // pair 15
#undef MIN16

    // fold row-mins across the 32 col positions (lane bits 0-4), atomicMin
    #pragma unroll
    for (int r = 0; r < 16; ++r) {
        float v = rmin[r];
        v = fminf(v, __shfl_xor(v, 1, 64));
        v = fminf(v, __shfl_xor(v, 2, 64));
        v = fminf(v, __shfl_xor(v, 4, 64));
        v = fminf(v, __shfl_xor(v, 8, 64));
        v = fminf(v, __shfl_xor(v, 16, 64));
        if (lo == 0) {
            int rr = (r & 3) + ((r >> 2) << 3) + (hi << 2);
            atomicMin((int*)&outMin[rw + rr], __float_as_int(fmaxf(v, 0.f)));
        }
    }
}

// ---------------- fused final reduction (one kernel, fixed tree) -----------
__global__ __launch_bounds__(1024) void chamfer_reduce(
    const float* __restrict__ minbuf, float* __restrict__ out)
{
    int tid = threadIdx.x;
    double s = 0.0;
    #pragma unroll
    for (int q = 0; q < 16; ++q) {      // 16 float4 per thread, fixed order
        float4 v = *reinterpret_cast<const float4*>(minbuf + (q * 1024 + tid) * 4);
        s += ((double)v.x + (double)v.y) + ((double)v.z + (double)v.w);
    }
    #pragma unroll
    for (int off = 32; off > 0; off >>= 1) s += __shfl_down(s, off, 64);
    __shared__ double sd[16];
    if ((tid & 63) == 0) sd[tid >> 6] = s;
    __syncthreads();
    if (tid == 0) {
        double t = 0.0;
        #pragma unroll
        for (int w = 0; w < 16; ++w) t += sd[w];
        out[0] = (float)(t / (double)(BATCHES * NPTS));
    }
}

extern "C" void kernel_launch(void* const* d_in, const int* in_sizes, int n_in,
                              void* d_out, int out_size, void* d_ws, size_t ws_size,
                              hipStream_t stream)
{
    const float* x = (const float*)d_in[0];
    const float* y = (const float*)d_in[1];
    float* out = (float*)d_out;

    // ws layout (~4.3 MB):
    float*    minall = (float*)d_ws;                       // 65536 f = 256 KB
    _Float16* pAx = (_Float16*)(minall + 65536);           // 1 MB each
    _Float16* pBx = pAx + (size_t)BATCHES * NPTS * 16;
    _Float16* pAy = pBx + (size_t)BATCHES * NPTS * 16;
    _Float16* pBy = pAy + (size_t)BATCHES * NPTS * 16;

    chamfer_prep<<<BATCHES * NPTS / 256, 256, 0, stream>>>(
        x, y, pAx, pBx, pAy, pBy, (int*)minall);
    chamfer_mfma<<<4096, 256, 0, stream>>>(pAx, pBx, pAy, pBy, minall);
    chamfer_reduce<<<1, 1024, 0, stream>>>(minall, out);
}

// Round 18
// 40.075 us; speedup vs baseline: 2.3708x; 1.1130x over previous
//
#include <hip/hip_runtime.h>

#define BATCHES 4
#define NPTS    8192
#define INF32   3.0e38f

typedef _Float16 f16x8  __attribute__((ext_vector_type(8)));
typedef float    f32x16 __attribute__((ext_vector_type(16)));

// ---------------- prep: pack A-format and B-format 16-slot f16 vectors ----
// A-vec (pt p):  [ph0..2, pl0..2, ph0..2, qh, ql, 1, 1, 0,0,0]
// B-vec (pt p):  [-2ph0..2, -2ph0..2, -2pl0..2, 1, 1, qh, ql, 0,0,0]
// dot(Avec(u), Bvec(v)) = |u|^2 + |v|^2 - 2*(uh.vh + ul.vh + uh.vl)  (err ~1e-5)
__device__ inline void fsplit(float v, _Float16& h, _Float16& l) {
    h = (_Float16)v;
    l = (_Float16)(v - (float)h);
}

__device__ inline void pack_point(float p0, float p1, float p2,
                                  _Float16* __restrict__ avec,
                                  _Float16* __restrict__ bvec)
{
    _Float16 h[3], l[3];
    fsplit(p0, h[0], l[0]); fsplit(p1, h[1], l[1]); fsplit(p2, h[2], l[2]);
    float q = fmaf(p2, p2, fmaf(p1, p1, p0 * p0));
    _Float16 qh, ql;
    fsplit(q, qh, ql);

    __align__(16) _Float16 av[16];
    __align__(16) _Float16 bv[16];
    #pragma unroll
    for (int k = 0; k < 3; ++k) {
        av[k]     = h[k];
        av[3 + k] = l[k];
        av[6 + k] = h[k];
        bv[k]     = (_Float16)(-2.0f * (float)h[k]);
        bv[3 + k] = bv[k];
        bv[6 + k] = (_Float16)(-2.0f * (float)l[k]);
    }
    av[9] = qh; av[10] = ql; av[11] = (_Float16)1.0f; av[12] = (_Float16)1.0f;
    bv[9] = (_Float16)1.0f; bv[10] = (_Float16)1.0f; bv[11] = qh; bv[12] = ql;
    av[13] = av[14] = av[15] = (_Float16)0.0f;
    bv[13] = bv[14] = bv[15] = (_Float16)0.0f;

    ((int4*)avec)[0] = ((int4*)av)[0]; ((int4*)avec)[1] = ((int4*)av)[1];
    ((int4*)bvec)[0] = ((int4*)bv)[0]; ((int4*)bvec)[1] = ((int4*)bv)[1];
}

__global__ __launch_bounds__(256) void chamfer_prep(
    const float* __restrict__ x, const float* __restrict__ y,
    _Float16* __restrict__ pAx, _Float16* __restrict__ pBx,
    _Float16* __restrict__ pAy, _Float16* __restrict__ pBy,
    int* __restrict__ mininit /* 65536 ints */)
{
    int i = blockIdx.x * 256 + threadIdx.x;     // point id 0..32767
    mininit[i]         = 0x7F7F7F7F;
    mininit[i + 32768] = 0x7F7F7F7F;

    const float* xp = x + (size_t)i * 3;
    const float* yp = y + (size_t)i * 3;
    pack_point(xp[0], xp[1], xp[2], pAx + (size_t)i * 16, pBx + (size_t)i * 16);
    pack_point(yp[0], yp[1], yp[2], pAy + (size_t)i * 16, pBy + (size_t)i * 16);
}

// ---------------- main: dual GEMM, E/O acc double-buffer (R15 = 21.8us) ----
// grid 2048 = dir(2) x batch(4) x rowstrip(64: 128 rows) x colchunk(4: 2048)
// 256 thr = 4 waves; wave owns ONE 32-row A-tile, loops 64 col-tiles as 32
// pairs with TWO explicit acc buffers: while pair B's MFMAs execute, pair
// A's results are consumed by 16 min3-shaped fminf. 2 pairs in flight is
// the empirical optimum (R9/R17 deeper variants regress: 120-reg cliff).
// Live ~120 regs (56 VGPR + 64 AGPR) -> 4 waves/SIMD at (256,4).
// A-frag: lane(row=l&31, k=(l>>5)*8+i); B-frag: lane(col=l&31, same k).
// D: col=l&31, row=(reg&3)+8*(reg>>2)+4*(l>>5)  [m74/m101].
__global__ __launch_bounds__(256, 4) void chamfer_mfma(
    const _Float16* __restrict__ pAx, const _Float16* __restrict__ pBx,
    const _Float16* __restrict__ pAy, const _Float16* __restrict__ pBy,
    float* __restrict__ minall /* [2][4][8192] */)
{
    int bid      = blockIdx.x;
    int dir      = bid >> 10;
    int b        = (bid >> 8) & 3;
    int rowstrip = (bid >> 2) & 63;    // 128 rows per block
    int colchunk = bid & 3;            // 2048 cols per block (64 tiles)
    int tid      = threadIdx.x;
    int wv       = tid >> 6, lane = tid & 63;
    int lo       = lane & 31, hi = lane >> 5;

    const _Float16* Adata = ((dir == 0) ? pAx : pAy) + (size_t)b * NPTS * 16;
    const _Float16* Bdata = ((dir == 0) ? pBy : pBx) + (size_t)b * NPTS * 16;
    float* outMin = minall + ((size_t)dir << 15) + (size_t)b * NPTS;

    int rw = rowstrip * 128 + wv * 32;   // wave's 32-row A-tile
    int c0 = colchunk * 2048;            // block's col base (64 tiles of 32)

    f16x8 af = *(const f16x8*)(Adata + ((size_t)(rw + lo) << 4) + (hi << 3));

    float rmin[16];
    #pragma unroll
    for (int r = 0; r < 16; ++r) rmin[r] = INF32;

    const f32x16 zero = {0.f,0.f,0.f,0.f,0.f,0.f,0.f,0.f,
                         0.f,0.f,0.f,0.f,0.f,0.f,0.f,0.f};

    auto loadB = [&](int t) -> f16x8 {   // t = col-tile 0..63
        return *(const f16x8*)(Bdata + ((size_t)(c0 + (t << 5) + lo) << 4) + (hi << 3));
    };

#define MIN3X16(P0, P1)                                                \
    _Pragma("unroll")                                                  \
    for (int r = 0; r < 16; ++r)                                       \
        rmin[r] = fminf(fminf(P0[r], P1[r]), rmin[r]);   /* v_min3 */

    // prologue: pair P0 in flight, P1 frags loaded
    f16x8 bcA0 = loadB(0), bcA1 = loadB(1);
    f32x16 accA0 = __builtin_amdgcn_mfma_f32_32x32x16_f16(af, bcA0, zero, 0, 0, 0);
    f32x16 accA1 = __builtin_amdgcn_mfma_f32_32x32x16_f16(af, bcA1, zero, 0, 0, 0);
    f16x8 bcB0 = loadB(2), bcB1 = loadB(3);
    f32x16 accB0, accB1;

    // iter q: consume P(2q),P(2q+1); issue P(2q+1),P(2q+2); load P(2q+2),P(2q+3)
    #pragma unroll 1
    for (int q = 0; q < 15; ++q) {
        accB0 = __builtin_amdgcn_mfma_f32_32x32x16_f16(af, bcB0, zero, 0, 0, 0);
        accB1 = __builtin_amdgcn_mfma_f32_32x32x16_f16(af, bcB1, zero, 0, 0, 0);
        bcA0 = loadB(4 * q + 4); bcA1 = loadB(4 * q + 5);
        MIN3X16(accA0, accA1)                    // pair 2q
        accA0 = __builtin_amdgcn_mfma_f32_32x32x16_f16(af, bcA0, zero, 0, 0, 0);
        accA1 = __builtin_amdgcn_mfma_f32_32x32x16_f16(af, bcA1, zero, 0, 0, 0);
        bcB0 = loadB(4 * q + 6); bcB1 = loadB(4 * q + 7);
        MIN3X16(accB0, accB1)                    // pair 2q+1
    }
    // epilogue: P31 issue, consume P30, P31
    accB0 = __builtin_amdgcn_mfma_f32_32x32x16_f16(af, bcB0, zero, 0, 0, 0);
    accB1 = __builtin_amdgcn_mfma_f32_32x32x16_f16(af, bcB1, zero, 0, 0, 0);
    MIN3X16(accA0, accA1)
    MIN3X16(accB0, accB1)
#undef MIN3X16

    // fold row-mins across the 32 col positions (lane bits 0-4), atomicMin
    #pragma unroll
    for (int r = 0; r < 16; ++r) {
        float v = rmin[r];
        v = fminf(v, __shfl_xor(v, 1, 64));
        v = fminf(v, __shfl_xor(v, 2, 64));
        v = fminf(v, __shfl_xor(v, 4, 64));
        v = fminf(v, __shfl_xor(v, 8, 64));
        v = fminf(v, __shfl_xor(v, 16, 64));
        if (lo == 0) {
            int rr = (r & 3) + ((r >> 2) << 3) + (hi << 2);
            atomicMin((int*)&outMin[rw + rr], __float_as_int(fmaxf(v, 0.f)));
        }
    }
}

// ---------------- fused final reduction (one kernel, fixed tree) -----------
__global__ __launch_bounds__(1024) void chamfer_reduce(
    const float* __restrict__ minbuf, float* __restrict__ out)
{
    int tid = threadIdx.x;
    double s = 0.0;
    #pragma unroll
    for (int q = 0; q < 16; ++q) {      // 16 float4 per thread, fixed order
        float4 v = *reinterpret_cast<const float4*>(minbuf + (q * 1024 + tid) * 4);
        s += ((double)v.x + (double)v.y) + ((double)v.z + (double)v.w);
    }
    #pragma unroll
    for (int off = 32; off > 0; off >>= 1) s += __shfl_down(s, off, 64);
    __shared__ double sd[16];
    if ((tid & 63) == 0) sd[tid >> 6] = s;
    __syncthreads();
    if (tid == 0) {
        double t = 0.0;
        #pragma unroll
        for (int w = 0; w < 16; ++w) t += sd[w];
        out[0] = (float)(t / (double)(BATCHES * NPTS));
    }
}

extern "C" void kernel_launch(void* const* d_in, const int* in_sizes, int n_in,
                              void* d_out, int out_size, void* d_ws, size_t ws_size,
                              hipStream_t stream)
{
    const float* x = (const float*)d_in[0];
    const float* y = (const float*)d_in[1];
    float* out = (float*)d_out;

    // ws layout (~4.3 MB):
    float*    minall = (float*)d_ws;                       // 65536 f = 256 KB
    _Float16* pAx = (_Float16*)(minall + 65536);           // 1 MB each
    _Float16* pBx = pAx + (size_t)BATCHES * NPTS * 16;
    _Float16* pAy = pBx + (size_t)BATCHES * NPTS * 16;
    _Float16* pBy = pAy + (size_t)BATCHES * NPTS * 16;

    chamfer_prep<<<BATCHES * NPTS / 256, 256, 0, stream>>>(
        x, y, pAx, pBx, pAy, pBy, (int*)minall);
    chamfer_mfma<<<2048, 256, 0, stream>>>(pAx, pBx, pAy, pBy, minall);
    chamfer_reduce<<<1, 1024, 0, stream>>>(minall, out);
}